// Round 14
// baseline (136.924 us; speedup 1.0000x reference)
//
#include <hip/hip_runtime.h>

#define NROWS 8192
#define NSPLIT 16
#define JT (NROWS / NSPLIT)  // 512 j's per split
#define L2E 1.4426950408889634f

typedef __attribute__((ext_vector_type(4))) float f32x4;
typedef __attribute__((ext_vector_type(8))) __bf16 bf16x8;
typedef __attribute__((ext_vector_type(4))) unsigned int u32x4;

__device__ __forceinline__ unsigned short f2bf(float x) {
  unsigned u = __float_as_uint(x);
  u += 0x7fffu + ((u >> 16) & 1u);
  return (unsigned short)(u >> 16);
}

// ---------------------------------------------------------------------------
// Kernel A: Wh = h@W (bf16, MFMA-B-fragment order), src=Wh@a1, dst=Wh@a2
// (exp2 domain). Fragment layout: slot (jc, nt, lane, e) holds
// Wh[j = 32*jc + 8*(lane>>4) + e][nt*16 + (lane&15)]
// ---------------------------------------------------------------------------
__global__ __launch_bounds__(256) void k_prep(
    const float* __restrict__ h, const float* __restrict__ W,
    const float* __restrict__ a, unsigned short* __restrict__ WhB,
    float* __restrict__ src, float* __restrict__ dst) {
  int i = blockIdx.x * 4 + (threadIdx.x >> 6);  // row
  int lane = threadIdx.x & 63;                  // feature
  const float* hrow = h + (size_t)i * 256;
  float s = 0.f;
#pragma unroll 4
  for (int k = 0; k < 256; k += 4) {
    float4 hv = *(const float4*)(hrow + k);
    s = fmaf(hv.x, W[(k + 0) * 64 + lane], s);
    s = fmaf(hv.y, W[(k + 1) * 64 + lane], s);
    s = fmaf(hv.z, W[(k + 2) * 64 + lane], s);
    s = fmaf(hv.w, W[(k + 3) * 64 + lane], s);
  }
  int nt = lane >> 4, c = lane & 15;
  int gi = (i >> 3) & 3, e = i & 7;
  int idx = ((((i >> 5) * 4 + nt) * 64) + c + 16 * gi) * 8 + e;
  WhB[idx] = f2bf(s);
  float v1 = s * a[lane];
  float v2 = s * a[64 + lane];
#pragma unroll
  for (int d = 32; d; d >>= 1) {
    v1 += __shfl_xor(v1, d);
    v2 += __shfl_xor(v2, d);
  }
  if (lane == 0) {
    src[i] = v1 * L2E;
    dst[i] = v2 * L2E;
  }
}

// ---------------------------------------------------------------------------
// Kernel A2: dmax = max_j dst[j]  (global scalar; 1 block)
// ---------------------------------------------------------------------------
__global__ __launch_bounds__(256) void k_dmax(
    const float* __restrict__ dst, float* __restrict__ dmax) {
  __shared__ float red[4];
  float v = -INFINITY;
  for (int i = threadIdx.x; i < NROWS; i += 256) v = fmaxf(v, dst[i]);
#pragma unroll
  for (int d = 32; d; d >>= 1) v = fmaxf(v, __shfl_xor(v, d));
  if ((threadIdx.x & 63) == 0) red[threadIdx.x >> 6] = v;
  __syncthreads();
  if (threadIdx.x == 0)
    *dmax = fmaxf(fmaxf(red[0], red[1]), fmaxf(red[2], red[3]));
}

// ---------------------------------------------------------------------------
// Kernel M: MINIMAL adj->bitmask pack. The isolated adj stream: one wave =
// one (row, seg-pair); two int4 loads (2 KB contiguous; consecutive blocks
// sweep 8 KB linearly — the same pattern the 6.9 TB/s poison fill uses);
// 8 ballots; 8-lane u64 stores. ~24 VGPR -> 32 waves/CU -> 64 KB/CU in
// flight. Layout: packed[(seg*NROWS + row)*4 + cw], bit l <-> col
// seg*256 + 4*l + cw.
// ---------------------------------------------------------------------------
__global__ __launch_bounds__(256) void k_mask(
    const int* __restrict__ adj, unsigned long long* __restrict__ packed) {
  int w = blockIdx.x * 4 + (threadIdx.x >> 6);  // 0 .. 131071
  int lane = threadIdx.x & 63;
  int row = w >> 4;
  int s0 = (w & 15) * 2;
  const int4* rp = (const int4*)(adj + (size_t)row * NROWS);
  int4 v0 = rp[s0 * 64 + lane];        // seg s0:  cols s0*256 + 4*lane ..+3
  int4 v1 = rp[s0 * 64 + 64 + lane];   // seg s0+1
  unsigned long long b0 = __ballot(v0.x > 0);
  unsigned long long b1 = __ballot(v0.y > 0);
  unsigned long long b2 = __ballot(v0.z > 0);
  unsigned long long b3 = __ballot(v0.w > 0);
  unsigned long long b4 = __ballot(v1.x > 0);
  unsigned long long b5 = __ballot(v1.y > 0);
  unsigned long long b6 = __ballot(v1.z > 0);
  unsigned long long b7 = __ballot(v1.w > 0);
  if (lane < 8) {
    int c = lane & 3;
    int seg = s0 + (lane >> 2);
    unsigned long long val = (lane == 0) ? b0 : (lane == 1) ? b1
                           : (lane == 2) ? b2 : (lane == 3) ? b3
                           : (lane == 4) ? b4 : (lane == 5) ? b5
                           : (lane == 6) ? b6 : b7;
    packed[((size_t)seg * NROWS + row) * 4 + c] = val;
  }
}

// ---------------------------------------------------------------------------
// Kernel B: masked-softmax + PV from the packed bitmask. One wave = one
// (16-row tile, split). NO transcendentals in the loop:
// 2^(lrelu(x)) = max(2^x, 2^(x/5)) factors as max(Ai*Bj, Ci*Dj) with
// Ai=2^(src-Mi), Ci=2^(src/5-Mi) per row and (Bj,Dj)=(2^dst, 2^(dst/5))
// per col (LDS float2 table). Absolute bound Mi = lrelu(src_i+dmax).
// Packed words: 512 B per (seg, 16-row group), wave-coalesced, L2-hot.
// ---------------------------------------------------------------------------
__global__ __launch_bounds__(256, 5) void k_attn(
    const unsigned long long* __restrict__ packed,
    const unsigned short* __restrict__ WhB,
    const float* __restrict__ src, const float* __restrict__ dst,
    const float* __restrict__ dmax,
    float* __restrict__ pl, float* __restrict__ pacc) {
  __shared__ float2 ldst2[JT];
  int task = blockIdx.x * 4 + (threadIdx.x >> 6);  // 0 .. 8191
  int sp = task >> 9;                              // split 0..15
  int mt = task & 511;                             // M-tile index
  int lane = threadIdx.x & 63;
  int r = lane & 15;  // row within tile / C col
  int g = lane >> 4;  // k-slot group
  int row0 = mt * 16;
  int jbase = sp * JT;

  // stage (2^dst, 2^(dst/5)) for this split's cols
  for (int k = threadIdx.x; k < JT; k += 256) {
    float dj = dst[jbase + k];
    ldst2[k] = make_float2(exp2f(dj), exp2f(0.2f * dj));
  }
  __syncthreads();

  float srcr = src[row0 + r];
  float vB = srcr + *dmax;
  float Mi = fmaxf(vB, 0.2f * vB);  // upper bound on this row's scores
  float Ai = exp2f(srcr - Mi);
  float Ci = exp2f(0.2f * srcr - Mi);

  float lrow = 0.f;
  f32x4 acc[4] = {f32x4{0.f, 0.f, 0.f, 0.f}, f32x4{0.f, 0.f, 0.f, 0.f},
                  f32x4{0.f, 0.f, 0.f, 0.f}, f32x4{0.f, 0.f, 0.f, 0.f}};
  const bf16x8* Bfr = (const bf16x8*)WhB;

#define PE(P, BIT, BV, DV)                         \
  {                                                \
    float e_ = fmaxf(Ai * (BV), Ci * (DV));        \
    (P) = ((unsigned)(BIT)&1u) ? e_ : 0.f;         \
  }
  // one 32-col half: 4 B-frags + 16 LDS floats + 8 PE -> pack -> 4 MFMA
#define HALF(JC, A0_, A1_, A2_, A3_, DOFF)                                 \
  {                                                                        \
    const bf16x8* bp = Bfr + (size_t)(JC) * 256 + lane;                    \
    bf16x8 b0 = bp[0];                                                     \
    bf16x8 b1 = bp[64];                                                    \
    bf16x8 b2 = bp[128];                                                   \
    bf16x8 b3 = bp[192];                                                   \
    const float4* dlp = (const float4*)(ldst2 + (DOFF));                   \
    float4 d0 = dlp[0], d1 = dlp[1], d2 = dlp[2], d3 = dlp[3];             \
    float p0, p1, p2, p3, p4, p5, p6, p7;                                  \
    PE(p0, (A0_), d0.x, d0.y)      PE(p1, (A1_), d0.z, d0.w)               \
    PE(p2, (A2_), d1.x, d1.y)      PE(p3, (A3_), d1.z, d1.w)               \
    PE(p4, (A0_) >> 1, d2.x, d2.y) PE(p5, (A1_) >> 1, d2.z, d2.w)          \
    PE(p6, (A2_) >> 1, d3.x, d3.y) PE(p7, (A3_) >> 1, d3.z, d3.w)          \
    lrow += ((p0 + p1) + (p2 + p3)) + ((p4 + p5) + (p6 + p7));             \
    unsigned q0, q1, q2, q3;                                               \
    asm("v_cvt_pk_bf16_f32 %0, %1, %2" : "=v"(q0) : "v"(p0), "v"(p1));     \
    asm("v_cvt_pk_bf16_f32 %0, %1, %2" : "=v"(q1) : "v"(p2), "v"(p3));     \
    asm("v_cvt_pk_bf16_f32 %0, %1, %2" : "=v"(q2) : "v"(p4), "v"(p5));     \
    asm("v_cvt_pk_bf16_f32 %0, %1, %2" : "=v"(q3) : "v"(p6), "v"(p7));     \
    u32x4 qv = {q0, q1, q2, q3};                                           \
    bf16x8 Af = __builtin_bit_cast(bf16x8, qv);                            \
    __builtin_amdgcn_s_setprio(1);                                         \
    acc[0] = __builtin_amdgcn_mfma_f32_16x16x32_bf16(Af, b0, acc[0], 0, 0, 0); \
    acc[1] = __builtin_amdgcn_mfma_f32_16x16x32_bf16(Af, b1, acc[1], 0, 0, 0); \
    acc[2] = __builtin_amdgcn_mfma_f32_16x16x32_bf16(Af, b2, acc[2], 0, 0, 0); \
    acc[3] = __builtin_amdgcn_mfma_f32_16x16x32_bf16(Af, b3, acc[3], 0, 0, 0); \
    __builtin_amdgcn_s_setprio(0);                                         \
  }

#pragma unroll 1
  for (int sg = 0; sg < 2; ++sg) {
    int seg = sp * 2 + sg;
    // 4 words (cw=0..3) for this lane's row: 32 B; 16-lane group = 512 B
    const ulonglong2* pwp =
        (const ulonglong2*)(packed + ((size_t)seg * NROWS + row0 + r) * 4);
    ulonglong2 wa = pwp[0];
    ulonglong2 wb = pwp[1];
    unsigned long long u0 = wa.x >> (2 * g);
    unsigned long long u1 = wa.y >> (2 * g);
    unsigned long long u2 = wb.x >> (2 * g);
    unsigned long long u3 = wb.y >> (2 * g);
#pragma unroll
    for (int inner = 0; inner < 4; ++inner) {
      int it = sg * 4 + inner;
      int jb = it * 64;
      unsigned long long a0 = u0 >> (inner * 16);
      unsigned long long a1 = u1 >> (inner * 16);
      unsigned long long a2 = u2 >> (inner * 16);
      unsigned long long a3 = u3 >> (inner * 16);
      unsigned long long h0 = a0 >> 8, h1 = a1 >> 8, h2 = a2 >> 8, h3 = a3 >> 8;
      int jc = sp * 16 + 2 * it;
      HALF(jc, a0, a1, a2, a3, jb + 8 * g)
      HALF(jc + 1, h0, h1, h2, h3, jb + 32 + 8 * g)
    }
  }
#undef HALF
#undef PE

  // row-sum of l across the 4 g-groups (lanes r, r+16, r+32, r+48)
  lrow += __shfl_xor(lrow, 16);
  lrow += __shfl_xor(lrow, 32);
  if (lane < 16) pl[sp * NROWS + row0 + lane] = lrow;
  // coalesced pacc: [sp][mt][nt][q][lane], lane = g*16+r
#pragma unroll
  for (int nt = 0; nt < 4; nt++)
#pragma unroll
    for (int q2 = 0; q2 < 4; q2++)
      pacc[((((size_t)sp * 512 + mt) * 4 + nt) * 4 + q2) * 64 + lane] = acc[nt][q2];
}

// ---------------------------------------------------------------------------
// Kernel C: combine = plain sums (all splits share the same reference Mi).
// pacc layout: [sp][mt][nt][q][g*16+r]; row = mt*16 + 4g+q, f = nt*16+r.
// ---------------------------------------------------------------------------
__global__ __launch_bounds__(256) void k_comb(
    const float* __restrict__ pl, const float* __restrict__ pacc,
    float* __restrict__ out) {
  int t = blockIdx.x * 256 + threadIdx.x;
  int row = t >> 6, f = t & 63;
  int mt = row >> 4, rem = row & 15, g = rem >> 2, q = rem & 3;
  int nt = f >> 4, r = f & 15;
  size_t base = ((((size_t)mt) * 4 + nt) * 4 + q) * 64 + g * 16 + r;
  float L = 0.f, o = 0.f;
#pragma unroll
  for (int s2 = 0; s2 < NSPLIT; s2++) {
    L += pl[s2 * NROWS + row];
    o += pacc[(size_t)s2 * (512 * 4 * 4 * 64) + base];
  }
  out[t] = o / L;
}

extern "C" void kernel_launch(void* const* d_in, const int* in_sizes, int n_in,
                              void* d_out, int out_size, void* d_ws, size_t ws_size,
                              hipStream_t stream) {
  const float* h = (const float*)d_in[0];
  const float* W = (const float*)d_in[1];
  const float* a = (const float*)d_in[2];
  const int* adj = (const int*)d_in[3];
  float* out = (float*)d_out;

  char* ws = (char*)d_ws;
  unsigned short* WhB = (unsigned short*)ws;                           // 1 MB
  float* src = (float*)(ws + 0x100000);                                // 32 KB
  float* dst = (float*)(ws + 0x108000);                                // 32 KB
  float* dmax = (float*)(ws + 0x110000);                               // 256 B
  float* pl = (float*)(ws + 0x110100);                                 // 512 KB
  float* pacc = (float*)(ws + 0x190100);                               // 32 MB
  unsigned long long* packed = (unsigned long long*)(ws + 0x2200000);  // 8 MB

  hipLaunchKernelGGL(k_prep, dim3(NROWS / 4), dim3(256), 0, stream, h, W, a, WhB, src, dst);
  hipLaunchKernelGGL(k_dmax, dim3(1), dim3(256), 0, stream, dst, dmax);
  hipLaunchKernelGGL(k_mask, dim3(32768), dim3(256), 0, stream, adj, packed);
  hipLaunchKernelGGL(k_attn, dim3(2048), dim3(256), 0, stream,
                     packed, WhB, src, dst, dmax, pl, pacc);
  hipLaunchKernelGGL(k_comb, dim3(NROWS * 64 / 256), dim3(256), 0, stream, pl, pacc, out);
}